// Round 6
// baseline (89.727 us; speedup 1.0000x reference)
//
#include <hip/hip_runtime.h>
#include <math.h>

#define L2PI4      7.3515082656373812f   // 4*log(2*pi)
#define HALF_L2PI4 3.6757541328186906f   // 2*log(2*pi)
#define LOG2E      1.4426950408889634f
#define LN2        0.6931471805599453f
#define C_HQ       0.7213475204444817f   // 0.5*log2(e)

__device__ __forceinline__ float frcp(float x)  { return __builtin_amdgcn_rcpf(x); }
__device__ __forceinline__ float flog2(float x) { return __builtin_amdgcn_logf(x); }
__device__ __forceinline__ float fexp2(float x) { return __builtin_amdgcn_exp2f(x); }

// ---------------------------------------------------------------------------
// kL1: lr for the 128 leaf children (K=4, mixture = state directly).
// Side-band: blocks 0..7 precompute tveP = exp(2*trans_var_p) (8000 floats).
// lr[cn*500 + t4], t4 = ((lp*5+llc)*5+lrc)*4+c, natural-log domain.
// ---------------------------------------------------------------------------
__global__ __launch_bounds__(256) void kL1(
    const float* __restrict__ sw, const float* __restrict__ smu,
    const float* __restrict__ svar,
    const float4* __restrict__ tmL4, const float4* __restrict__ tvL4,
    const float4* __restrict__ tmR4, const float4* __restrict__ tvR4,
    const float* __restrict__ tvarp, float* __restrict__ tveP,
    float* __restrict__ lr)
{
    int cn = blockIdx.x, side = cn & 1, tid = threadIdx.x;
    if (cn < 8) {
        for (int i = tid; i < 1000; i += 256) {
            int j = cn * 1000 + i;
            tveP[j] = __expf(2.f * tvarp[j]);
        }
    }
    __shared__ float s_cm[80], s_cve[80], s_cw2[20];
    if (tid < 80) {
        s_cm[tid]  = smu[cn * 80 + tid];
        s_cve[tid] = __expf(2.f * svar[cn * 80 + tid]);
        if (tid < 20) s_cw2[tid] = (sw[cn * 20 + tid] - HALF_L2PI4) * LOG2E;
    }
    __syncthreads();
    const float4* tm = side ? tmR4 : tmL4;
    const float4* tv = side ? tvR4 : tvL4;
    for (int e = tid; e < 500; e += 256) {
        int c = e & 3, r = e >> 2;
        int lo = r % 5, r2 = r / 5, lp = r2 % 5, lc2 = r2 / 5;
        int idx = side ? (((lp * 5 + lo) * 5 + lc2) * 4 + c)
                       : (((lp * 5 + lc2) * 5 + lo) * 4 + c);
        float4 tmo = tm[idx];
        float4 tvr = tv[idx];
        float4 tvo = make_float4(__expf(2.f * tvr.x), __expf(2.f * tvr.y),
                                 __expf(2.f * tvr.z), __expf(2.f * tvr.w));
        float vals[4];
        #pragma unroll
        for (int k = 0; k < 4; ++k) {
            int ci = (lc2 * 4 + k) * 4;
            float s0 = s_cve[ci+0] + tvo.x, s1 = s_cve[ci+1] + tvo.y;
            float s2 = s_cve[ci+2] + tvo.z, s3 = s_cve[ci+3] + tvo.w;
            float d0 = s_cm[ci+0] - tmo.x, d1 = s_cm[ci+1] - tmo.y;
            float d2 = s_cm[ci+2] - tmo.z, d3 = s_cm[ci+3] - tmo.w;
            float p01 = s0 * s1, p23 = s2 * s3;
            float q01 = fmaf(d0 * d0, s1, d1 * d1 * s0);
            float q23 = fmaf(d2 * d2, s3, d3 * d3 * s2);
            float P = p01 * p23;
            float Q = fmaf(q01, p23, q23 * p01);
            vals[k] = fmaf(-0.5f, flog2(P), fmaf(-C_HQ, Q * frcp(P), s_cw2[lc2 * 4 + k]));
        }
        float M = fmaxf(fmaxf(vals[0], vals[1]), fmaxf(vals[2], vals[3]));
        float S = fexp2(vals[0]-M) + fexp2(vals[1]-M)
                + fexp2(vals[2]-M) + fexp2(vals[3]-M);
        lr[(size_t)cn * 500 + idx] = (M + flog2(S)) * LN2;
    }
}

// ---------------------------------------------------------------------------
// kAB: one launch per parent-level m. block = (p, side, lc, lp), grid 50*m.
// Phase 1: rebuild child cn's 400-comp mixture (w2, mu, ve) IN REGISTERS from
//          lr_prev(2cn), lr_prev(2cn+1) + trans_p + state(childOff+cn), label lc.
// Phase 2: j-outer lse over the 400 comps, 5 (lo,c) outputs per wave.
// __launch_bounds__(256,3): VGPR cap ~168 — the round-4/5 kernels were
// 64-VGPR-capped by the occupancy heuristic and spilled the fragment to
// scratch (kLvl: VGPR_Count=64, 25% VALUBusy, flat 47us).
// ---------------------------------------------------------------------------
__global__ __launch_bounds__(256, 3) void kAB(
    const float* __restrict__ lrP, float* __restrict__ lrC,
    const float* __restrict__ sw, const float* __restrict__ smu,
    const float* __restrict__ svar, int childOff,
    const float* __restrict__ tw, const float4* __restrict__ tmp4,
    const float4* __restrict__ tep4,
    const float4* __restrict__ tmL4, const float4* __restrict__ tvL4,
    const float4* __restrict__ tmR4, const float4* __restrict__ tvR4,
    int log2m)
{
    int bid = blockIdx.x;
    int p = bid & ((1 << log2m) - 1), sl = bid >> log2m;
    int side = (sl >= 25) ? 1 : 0;
    int r0 = sl - side * 25;
    int lc = r0 / 5, lp = r0 - lc * 5;
    int tid = threadIdx.x, lane = tid & 63, wave = tid >> 6;
    int cn = 2 * p + side;
    int node = childOff + cn;

    __shared__ float s_sm[16], s_sve[16], s_swl[4];
    if (tid < 16) {
        s_sm[tid]  = smu[node * 80 + lc * 16 + tid];
        s_sve[tid] = __expf(2.f * svar[node * 80 + lc * 16 + tid]);
        if (tid < 4) s_swl[tid] = sw[node * 20 + lc * 4 + tid];
    }
    __syncthreads();

    const float* lrL = lrP + (size_t)(2 * cn) * 500;
    const float* lrR = lrP + (size_t)(2 * cn + 1) * 500;

    // ---- Phase 1: child fragment in registers --------------------------
    float w2r[7]; float4 cm[7], cve[7];
    #pragma unroll
    for (int i = 0; i < 7; ++i) {
        int kk = lane + (i << 6);
        int k = kk < 400 ? kk : 399;
        int c2 = k & 3, ks = (k >> 2) & 3, r = k >> 4;     // r = llc2*5+lrc2
        int t4 = (lc * 25 + r) * 4 + c2;
        float csv = lrL[t4] + lrR[t4] + tw[t4];
        float4 m2 = tmp4[t4], e2 = tep4[t4];
        float base2 = (csv + s_swl[ks] - L2PI4) * LOG2E;   // incl. next-level pre-sub
        float L = 0.f, Qn = 0.f;
        float4 mu, ve;
        {
            float v1s = s_sve[ks*4+0], m1 = s_sm[ks*4+0];
            float s = v1s + e2.x, rs = frcp(s), df = m1 - m2.x;
            L += flog2(s); Qn = fmaf(df * df, rs, Qn);
            mu.x = fmaf(m1, e2.x, m2.x * v1s) * rs; ve.x = v1s * e2.x * rs;
        }
        {
            float v1s = s_sve[ks*4+1], m1 = s_sm[ks*4+1];
            float s = v1s + e2.y, rs = frcp(s), df = m1 - m2.y;
            L += flog2(s); Qn = fmaf(df * df, rs, Qn);
            mu.y = fmaf(m1, e2.y, m2.y * v1s) * rs; ve.y = v1s * e2.y * rs;
        }
        {
            float v1s = s_sve[ks*4+2], m1 = s_sm[ks*4+2];
            float s = v1s + e2.z, rs = frcp(s), df = m1 - m2.z;
            L += flog2(s); Qn = fmaf(df * df, rs, Qn);
            mu.z = fmaf(m1, e2.z, m2.z * v1s) * rs; ve.z = v1s * e2.z * rs;
        }
        {
            float v1s = s_sve[ks*4+3], m1 = s_sm[ks*4+3];
            float s = v1s + e2.w, rs = frcp(s), df = m1 - m2.w;
            L += flog2(s); Qn = fmaf(df * df, rs, Qn);
            mu.w = fmaf(m1, e2.w, m2.w * v1s) * rs; ve.w = v1s * e2.w * rs;
        }
        w2r[i] = (kk < 400) ? fmaf(-0.5f, fmaf(Qn, LOG2E, L), base2) : -1e30f;
        cm[i] = mu; cve[i] = ve;
    }

    // ---- Phase 2: j-outer lse, 5 outputs per wave -----------------------
    const float4* tmf = side ? tmR4 : tmL4;
    const float4* tvf = side ? tvR4 : tvL4;
    size_t lrb = (size_t)cn * 500;
    #pragma unroll
    for (int j = 0; j < 5; ++j) {
        int o = wave + 4 * j, lo = o >> 2, c = o & 3;
        int idx = side ? (((lp * 5 + lo) * 5 + lc) * 4 + c)
                       : (((lp * 5 + lc) * 5 + lo) * 4 + c);
        float4 tmo = tmf[idx];
        float4 tvr = tvf[idx];
        float4 tvo = make_float4(__expf(2.f * tvr.x), __expf(2.f * tvr.y),
                                 __expf(2.f * tvr.z), __expf(2.f * tvr.w));
        float vals[7], M;
        #pragma unroll
        for (int i = 0; i < 7; ++i) {
            float s0 = cve[i].x + tvo.x, s1 = cve[i].y + tvo.y;
            float s2 = cve[i].z + tvo.z, s3 = cve[i].w + tvo.w;
            float d0 = cm[i].x - tmo.x, d1 = cm[i].y - tmo.y;
            float d2 = cm[i].z - tmo.z, d3 = cm[i].w - tmo.w;
            float p01 = s0 * s1, p23 = s2 * s3;
            float q01 = fmaf(d0 * d0, s1, d1 * d1 * s0);
            float q23 = fmaf(d2 * d2, s3, d3 * d3 * s2);
            float P = p01 * p23;
            float Q = fmaf(q01, p23, q23 * p01);
            float v = fmaf(-0.5f, flog2(P), fmaf(-C_HQ, Q * frcp(P), w2r[i]));
            vals[i] = v;
            M = (i == 0) ? v : fmaxf(M, v);
        }
        #pragma unroll
        for (int s = 32; s; s >>= 1) M = fmaxf(M, __shfl_xor(M, s));
        float a0 = fexp2(vals[0] - M) + fexp2(vals[1] - M);
        float a1 = fexp2(vals[2] - M) + fexp2(vals[3] - M);
        float a2 = fexp2(vals[4] - M) + fexp2(vals[5] - M);
        float S = a0 + a1 + a2 + fexp2(vals[6] - M);
        #pragma unroll
        for (int s = 32; s; s >>= 1) S += __shfl_xor(S, s);
        if (lane == 0) lrC[lrb + idx] = (M + flog2(S)) * LN2;
    }
}

// ---------------------------------------------------------------------------
// kFin: root mixture (w, mu, var) -> d_out. 2000 outputs, one per thread.
// ---------------------------------------------------------------------------
__global__ __launch_bounds__(256) void kFin(
    const float* __restrict__ lrC,
    const float* __restrict__ sw, const float* __restrict__ smu,
    const float* __restrict__ svar, int rootNode,
    const float* __restrict__ tw, const float4* __restrict__ tmp4,
    const float4* __restrict__ tvp4, const float4* __restrict__ tep4,
    float* __restrict__ outw, float4* __restrict__ outmu4,
    float4* __restrict__ outvar4)
{
    int e = blockIdx.x * 256 + threadIdx.x;
    if (e >= 2000) return;
    int c = e & 3, ks = (e >> 2) & 3, r = e >> 4;
    int lrc = r % 5, r2 = r / 5, llc = r2 % 5, lp = r2 / 5;
    int t4 = ((lp * 5 + llc) * 5 + lrc) * 4 + c;
    float csv = lrC[t4] + lrC[500 + t4] + tw[t4];
    float4 m2 = tmp4[t4], v2 = tvp4[t4], e2 = tep4[t4];
    int sb = rootNode * 80 + (lp * 4 + ks) * 4;
    float base = csv + sw[rootNode * 20 + lp * 4 + ks] - HALF_L2PI4;
    float scale = 0.f;
    float4 pmu, pvar;
    {
        float m1 = smu[sb+0], v1 = svar[sb+0], v1s = __expf(2.f * v1);
        float s = v1s + e2.x, rs = frcp(s), ls = flog2(s) * LN2, df = m1 - m2.x;
        scale += ls + df * df * rs;
        pmu.x = fmaf(m1, e2.x, m2.x * v1s) * rs; pvar.x = v1 + v2.x - 0.5f * ls;
    }
    {
        float m1 = smu[sb+1], v1 = svar[sb+1], v1s = __expf(2.f * v1);
        float s = v1s + e2.y, rs = frcp(s), ls = flog2(s) * LN2, df = m1 - m2.y;
        scale += ls + df * df * rs;
        pmu.y = fmaf(m1, e2.y, m2.y * v1s) * rs; pvar.y = v1 + v2.y - 0.5f * ls;
    }
    {
        float m1 = smu[sb+2], v1 = svar[sb+2], v1s = __expf(2.f * v1);
        float s = v1s + e2.z, rs = frcp(s), ls = flog2(s) * LN2, df = m1 - m2.z;
        scale += ls + df * df * rs;
        pmu.z = fmaf(m1, e2.z, m2.z * v1s) * rs; pvar.z = v1 + v2.z - 0.5f * ls;
    }
    {
        float m1 = smu[sb+3], v1 = svar[sb+3], v1s = __expf(2.f * v1);
        float s = v1s + e2.w, rs = frcp(s), ls = flog2(s) * LN2, df = m1 - m2.w;
        scale += ls + df * df * rs;
        pmu.w = fmaf(m1, e2.w, m2.w * v1s) * rs; pvar.w = v1 + v2.w - 0.5f * ls;
    }
    outw[e]    = fmaf(-0.5f, scale, base);
    outmu4[e]  = pmu;
    outvar4[e] = pvar;
}

// ---------------------------------------------------------------------------
// Launcher: 8 launches, no atomics. ws layout (floats):
//   lrA[64000] lrB[64000] tveP[8000]
// ---------------------------------------------------------------------------
extern "C" void kernel_launch(void* const* d_in, const int* in_sizes, int n_in,
                              void* d_out, int out_size, void* d_ws, size_t ws_size,
                              hipStream_t stream) {
    (void)in_sizes; (void)n_in; (void)out_size; (void)ws_size;
    const float* sw      = (const float*)d_in[0];
    const float* smu     = (const float*)d_in[1];
    const float* svar    = (const float*)d_in[2];
    const float* tw      = (const float*)d_in[3];
    const float* tmu_p   = (const float*)d_in[4];
    const float* tmu_lc  = (const float*)d_in[5];
    const float* tmu_rc  = (const float*)d_in[6];
    const float* tvar_p  = (const float*)d_in[7];
    const float* tvar_lc = (const float*)d_in[8];
    const float* tvar_rc = (const float*)d_in[9];

    float* ws   = (float*)d_ws;
    float* lrA  = ws;
    float* lrB  = lrA + 64000;
    float* tveP = lrB + 64000;
    float* out  = (float*)d_out;

    hipLaunchKernelGGL(kL1, dim3(128), dim3(256), 0, stream,
                       sw, smu, svar,
                       (const float4*)tmu_lc, (const float4*)tvar_lc,
                       (const float4*)tmu_rc, (const float4*)tvar_rc,
                       tvar_p, tveP, lrA);

    // (m, childOff): children of level-m parents live at childOff..childOff+2m-1
    const int childOffs[6] = {128, 192, 224, 240, 248, 252};
    float* lrP = lrA;
    float* lrC = lrB;
    int li = 0;
    for (int lg = 5; lg >= 0; --lg, ++li) {
        int m = 1 << lg;
        hipLaunchKernelGGL(kAB, dim3(50 * m), dim3(256), 0, stream,
                           lrP, lrC,
                           sw, smu, svar, childOffs[li],
                           tw, (const float4*)tmu_p, (const float4*)tveP,
                           (const float4*)tmu_lc, (const float4*)tvar_lc,
                           (const float4*)tmu_rc, (const float4*)tvar_rc,
                           lg);
        float* t = lrP; lrP = lrC; lrC = t;
    }
    // after loop, last level's output is in lrP (entries 0,1)
    hipLaunchKernelGGL(kFin, dim3(8), dim3(256), 0, stream,
                       lrP, sw, smu, svar, 254,
                       tw, (const float4*)tmu_p, (const float4*)tvar_p,
                       (const float4*)tveP,
                       out, (float4*)(out + 2000), (float4*)(out + 10000));
}